// Round 12
// baseline (162.110 us; speedup 1.0000x reference)
//
#include <hip/hip_runtime.h>
#include <cstdint>
#include <cstddef>

// Problem constants: B=1024, T=12, D=512
#define Bsz 1024
#define Tsz 12
#define Dsz 512

#define TILE 128   // block tile 128(j) x 128(i); 4 waves as 2x2 of 64x64
#define BK   32    // K-chunk (32 f16 = 64 B = 4 x 16B chunks per row)
#define NIB  (Bsz / TILE)   // 8 i-tiles per column

typedef _Float16 f16x8 __attribute__((ext_vector_type(8)));
typedef float    f32x4 __attribute__((ext_vector_type(4)));

// fp32x8 -> f16 hi/lo split (hi = rne(x), lo = rne(x - hi)), 16B outputs.
__device__ __forceinline__ void cvt_store8(const float4 a, const float4 b,
                                           _Float16* hp, _Float16* lp) {
    const float x[8] = {a.x, a.y, a.z, a.w, b.x, b.y, b.z, b.w};
    f16x8 h, l;
#pragma unroll
    for (int i = 0; i < 8; ++i) {
        const _Float16 hi = (_Float16)x[i];
        h[i] = hi;
        l[i] = (_Float16)(x[i] - (float)hi);
    }
    *(f16x8*)hp = h;
    *(f16x8*)lp = l;
}

// Async global->LDS DMA, 16 B per lane (dest = wave-uniform base + lane*16).
__device__ __forceinline__ void async_load16(const void* g, void* l) {
    __builtin_amdgcn_global_load_lds(
        (const __attribute__((address_space(1))) void*)g,
        (__attribute__((address_space(3))) void*)l, 16, 0, 0);
}

// Pre-split pass: convert P and X ([B,T,D] fp32, t-chunk) into compact
// [nt][B][D] f16 hi/lo arrays. Each element converted exactly ONCE.
__global__ __launch_bounds__(256) void split_kernel(
    const float* __restrict__ P, const float* __restrict__ X,
    _Float16* __restrict__ Ph, _Float16* __restrict__ Pl,
    _Float16* __restrict__ Xh, _Float16* __restrict__ Xl,
    int t0, int nt)
{
    const int e8 = blockIdx.x * 256 + threadIdx.x;   // 8-elem group index
    const int n8 = nt * Bsz * (Dsz / 8);
    if (e8 >= n8) return;
    const int d8   = e8 & (Dsz / 8 - 1);
    const int rest = e8 >> 6;               // tz*Bsz + b
    const int b    = rest & (Bsz - 1);
    const int tz   = rest >> 10;
    const size_t src = ((size_t)b * Tsz + (t0 + tz)) * Dsz + d8 * 8;
    const size_t dst = ((size_t)tz * Bsz + b) * Dsz + d8 * 8;
    const float4 p0 = *(const float4*)(P + src);
    const float4 p1 = *(const float4*)(P + src + 4);
    const float4 x0 = *(const float4*)(X + src);
    const float4 x1 = *(const float4*)(X + src + 4);
    cvt_store8(p0, p1, Ph + dst, Pl + dst);
    cvt_store8(x0, x1, Xh + dst, Xl + dst);
}

// Fused GEMM + tile softmax-partials, double-buffered LDS with raw
// s_waitcnt/s_barrier so the prefetch DMA for iter k+1 stays in flight
// across iter k's compute (a __syncthreads() would drain it: the m97-
// structure stall). Per iter: wait(batch k, issued one iter ago) ->
// barrier -> frag reads (buf k) -> issue DMA k+1 (buf k^1) -> 48 MFMA.
__global__ __launch_bounds__(256, 2) void gemm_fused_kernel(
    const _Float16* __restrict__ Ph, const _Float16* __restrict__ Pl,
    const _Float16* __restrict__ Xh, const _Float16* __restrict__ Xl,
    float* __restrict__ pm,        // [Tsz*Bsz*NIB] tile max
    float* __restrict__ ps,        // [Tsz*Bsz*NIB] tile sum exp
    int*   __restrict__ pa,        // [Tsz*Bsz*NIB] tile argmax (global i)
    float* __restrict__ diag,      // [Tsz*Bsz]
    int t0)
{
    const int tz = blockIdx.z;
    const int t  = t0 + tz;
    const int bx = blockIdx.x;
    const int ib = bx * TILE;           // i tile (n-dim)
    const int jb = blockIdx.y * TILE;   // j tile (m-dim)
    const int tid  = threadIdx.x;
    const int lane = tid & 63;
    const int w    = tid >> 6;          // wave 0..3
    const int jw   = (w & 1) * 64;      // wave j-offset
    const int iw   = (w >> 1) * 64;     // wave i-offset
    const int ml   = lane & 15;
    const int quad = lane >> 4;

    __shared__ _Float16 Psh[2][TILE][BK];  // P hi, double-buffered
    __shared__ _Float16 Psl[2][TILE][BK];  // P lo
    __shared__ _Float16 Xsh[2][TILE][BK];  // X hi
    __shared__ _Float16 Xsl[2][TILE][BK];  // X lo
    __shared__ float sm_m[TILE][2];
    __shared__ float sm_s[TILE][2];
    __shared__ int   sm_a[TILE][2];

    f32x4 acc[4][4];
#pragma unroll
    for (int r = 0; r < 4; ++r)
#pragma unroll
        for (int c = 0; c < 4; ++c) acc[r][c] = (f32x4){0.f, 0.f, 0.f, 0.f};

    const size_t toff = (size_t)tz * Bsz * Dsz;
    // Wave w stages one whole array per iter: 8 DMA issues x 16 rows.
    const _Float16* gbase;
    _Float16* lb0;
    _Float16* lb1;
    if      (w == 0) { gbase = Ph + toff + (size_t)jb * Dsz; lb0 = &Psh[0][0][0]; lb1 = &Psh[1][0][0]; }
    else if (w == 1) { gbase = Pl + toff + (size_t)jb * Dsz; lb0 = &Psl[0][0][0]; lb1 = &Psl[1][0][0]; }
    else if (w == 2) { gbase = Xh + toff + (size_t)ib * Dsz; lb0 = &Xsh[0][0][0]; lb1 = &Xsh[1][0][0]; }
    else             { gbase = Xl + toff + (size_t)ib * Dsz; lb0 = &Xsl[0][0][0]; lb1 = &Xsl[1][0][0]; }
    const int srow = lane >> 2;        // 0..15 row within issue-group
    const int sch  = lane & 3;         // 16B chunk within 64B row

    // ---- prologue: stage k0=0 into buffer 0 ----
#pragma unroll
    for (int u = 0; u < 8; ++u) {
        const int row = u * 16 + srow;
        async_load16(gbase + (size_t)row * Dsz + sch * 8, lb0 + u * 16 * BK);
    }

    for (int it = 0; it < Dsz / BK; ++it) {
        const int kb = it & 1;
        _Float16* lcur = kb ? lb1 : lb0;
        _Float16* lnxt = kb ? lb0 : lb1;
        const _Float16 (*Pch)[BK] = kb ? Psh[1] : Psh[0];
        const _Float16 (*Pcl)[BK] = kb ? Psl[1] : Psl[0];
        const _Float16 (*Xch)[BK] = kb ? Xsh[1] : Xsh[0];
        const _Float16 (*Xcl)[BK] = kb ? Xsl[1] : Xsl[0];
        (void)lcur;

        // batch for THIS buffer was issued one full iteration ago (or in
        // the prologue) -> the drain is cheap. Raw barrier: no compiler-
        // forced drain of the upcoming prefetch.
        __builtin_amdgcn_s_waitcnt(0x0F70);   // vmcnt(0), lgkm/exp free
        __builtin_amdgcn_s_barrier();
        asm volatile("" ::: "memory");        // no ds_read hoisting

        // ---- fragments from current buffer ----
        f16x8 ah[4], al[4], bh[4], bl[4];
#pragma unroll
        for (int r = 0; r < 4; ++r) {
            ah[r] = *(const f16x8*)&Pch[jw + r * 16 + ml][quad * 8];
            al[r] = *(const f16x8*)&Pcl[jw + r * 16 + ml][quad * 8];
        }
#pragma unroll
        for (int c = 0; c < 4; ++c) {
            bh[c] = *(const f16x8*)&Xch[iw + c * 16 + ml][quad * 8];
            bl[c] = *(const f16x8*)&Xcl[iw + c * 16 + ml][quad * 8];
        }

        // ---- prefetch next K-chunk into the other buffer ----
        const int kn = (it + 1) * BK;
        if (kn < Dsz) {
#pragma unroll
            for (int u = 0; u < 8; ++u) {
                const int row = u * 16 + srow;
                async_load16(gbase + (size_t)row * Dsz + kn + sch * 8,
                             lnxt + u * 16 * BK);
            }
        }

        // ---- MFMA: hi*hi + hi*lo + lo*hi ----
#pragma unroll
        for (int r = 0; r < 4; ++r)
#pragma unroll
            for (int c = 0; c < 4; ++c) {
                acc[r][c] = __builtin_amdgcn_mfma_f32_16x16x32_f16(ah[r], bh[c], acc[r][c], 0, 0, 0);
                acc[r][c] = __builtin_amdgcn_mfma_f32_16x16x32_f16(ah[r], bl[c], acc[r][c], 0, 0, 0);
                acc[r][c] = __builtin_amdgcn_mfma_f32_16x16x32_f16(al[r], bh[c], acc[r][c], 0, 0, 0);
            }
        asm volatile("" ::: "memory");
    }

    // ---- diag extraction (global index test) ----
#pragma unroll
    for (int r = 0; r < 4; ++r)
#pragma unroll
        for (int v = 0; v < 4; ++v) {
            const int jg = jb + jw + r * 16 + quad * 4 + v;
#pragma unroll
            for (int c = 0; c < 4; ++c) {
                const int ig = ib + iw + c * 16 + ml;
                if (ig == jg) diag[(size_t)t * Bsz + jg] = acc[r][c][v];
            }
        }

    // ---- per-row (j) partial over this wave's 64-i slice ----
    // acc[r][c][v] sits at row j = jw+r*16+quad*4+v, col i = iw+c*16+ml.
#pragma unroll
    for (int r = 0; r < 4; ++r)
#pragma unroll
        for (int v = 0; v < 4; ++v) {
            float m = acc[r][0][v];
            int   ai = iw + ml;
#pragma unroll
            for (int c = 1; c < 4; ++c) {
                const float val = acc[r][c][v];
                if (val > m) { m = val; ai = iw + c * 16 + ml; }
            }
#pragma unroll
            for (int off = 1; off < 16; off <<= 1) {
                float om = __shfl_xor(m, off);
                int   oi = __shfl_xor(ai, off);
                if (om > m || (om == m && oi < ai)) { m = om; ai = oi; }
            }
            float s = 0.0f;
#pragma unroll
            for (int c = 0; c < 4; ++c) s += __expf(acc[r][c][v] - m);
#pragma unroll
            for (int off = 1; off < 16; off <<= 1) s += __shfl_xor(s, off);

            if (ml == 0) {
                const int row = jw + r * 16 + quad * 4 + v;
                sm_m[row][iw >> 6] = m;
                sm_s[row][iw >> 6] = s;
                sm_a[row][iw >> 6] = ib + ai;   // global i
            }
        }
    __syncthreads();

    // ---- combine the two i-halves, write tile partials ----
    if (tid < TILE) {
        const int row = tid;
        const float m0 = sm_m[row][0], m1 = sm_m[row][1];
        const float s0 = sm_s[row][0], s1 = sm_s[row][1];
        float M; int A;
        if (m1 > m0) { M = m1; A = sm_a[row][1]; }   // tie -> half 0 (smaller i)
        else         { M = m0; A = sm_a[row][0]; }
        const float S = s0 * __expf(m0 - M) + s1 * __expf(m1 - M);
        const size_t slot = ((size_t)t * Bsz + (jb + row)) * NIB + bx;
        pm[slot] = M;
        ps[slot] = S;
        pa[slot] = A;
    }
}

__global__ void zero_out_kernel(float* out) {
    if (threadIdx.x < 2) out[threadIdx.x] = 0.0f;
}

// One thread per (t,j) column: merge NIB tile partials, 48 block atomics.
__global__ __launch_bounds__(256) void combine_kernel(
    const float* __restrict__ pm,
    const float* __restrict__ ps,
    const int*   __restrict__ pa,
    const float* __restrict__ diag,
    float* __restrict__ out)
{
    const int col = blockIdx.x * 256 + threadIdx.x;   // 0..Tsz*Bsz-1
    const int j = col & (Bsz - 1);

    const size_t base = (size_t)col * NIB;
    float M = pm[base]; int A = pa[base];
#pragma unroll
    for (int b = 1; b < NIB; ++b) {
        const float mb = pm[base + b];
        if (mb > M) { M = mb; A = pa[base + b]; }   // tie -> earlier b = smaller i
    }
    float S = 0.0f;
#pragma unroll
    for (int b = 0; b < NIB; ++b) S += ps[base + b] * __expf(pm[base + b] - M);

    const float lse = M + logf(S);
    float sl = lse - diag[col];
    float sc = (A == j) ? 1.0f : 0.0f;

#pragma unroll
    for (int off = 1; off < 64; off <<= 1) {
        sl += __shfl_xor(sl, off);
        sc += __shfl_xor(sc, off);
    }

    __shared__ float wl[4], wc[4];
    const int w = threadIdx.x >> 6;
    if ((threadIdx.x & 63) == 0) { wl[w] = sl; wc[w] = sc; }
    __syncthreads();
    if (threadIdx.x == 0) {
        const float inv = 1.0f / (float)(Bsz * Tsz);
        atomicAdd(&out[0], (wl[0] + wl[1] + wl[2] + wl[3]) * inv);  // -loss
        atomicAdd(&out[1], (wc[0] + wc[1] + wc[2] + wc[3]) * inv);  // accuracy
    }
}

extern "C" void kernel_launch(void* const* d_in, const int* in_sizes, int n_in,
                              void* d_out, int out_size, void* d_ws, size_t ws_size,
                              hipStream_t stream) {
    const float* P = (const float*)d_in[0];  // predictions [B,T,D]
    const float* X = (const float*)d_in[1];  // x_future_encoded [B,T,D]
    float* out = (float*)d_out;

    const size_t ncol  = (size_t)Bsz * Tsz;          // 12288
    const size_t nslot = ncol * NIB;                 // 98304
    float* pm   = (float*)d_ws;
    float* ps   = pm + nslot;
    int*   pa   = (int*)(ps + nslot);
    float* diag = (float*)(pa + nslot);
    char*  splitbuf = (char*)(diag + ncol);
    splitbuf = (char*)(((uintptr_t)splitbuf + 255) & ~(uintptr_t)255);

    const size_t perArr = (size_t)Bsz * Dsz * sizeof(_Float16);  // 1 MiB per t
    const size_t perT   = 4 * perArr;                            // 4 MiB per t
    const size_t used   = (size_t)(splitbuf - (char*)d_ws);
    size_t avail = ws_size > used ? ws_size - used : 0;
    int ntc = (int)(avail / perT);
    if (ntc > Tsz) ntc = Tsz;
    if (ntc < 1) ntc = 1;

    for (int t0 = 0; t0 < Tsz; t0 += ntc) {
        const int nt = (Tsz - t0) < ntc ? (Tsz - t0) : ntc;
        _Float16* Ph = (_Float16*)splitbuf;
        _Float16* Pl = Ph + (size_t)nt * Bsz * Dsz;
        _Float16* Xh = Pl + (size_t)nt * Bsz * Dsz;
        _Float16* Xl = Xh + (size_t)nt * Bsz * Dsz;

        const int n8 = nt * Bsz * (Dsz / 8);
        split_kernel<<<dim3((n8 + 255) / 256), dim3(256), 0, stream>>>(
            P, X, Ph, Pl, Xh, Xl, t0, nt);

        gemm_fused_kernel<<<dim3(NIB, Bsz / TILE, nt), dim3(256), 0, stream>>>(
            Ph, Pl, Xh, Xl, pm, ps, pa, diag, t0);
    }

    zero_out_kernel<<<dim3(1), dim3(64), 0, stream>>>(out);

    combine_kernel<<<dim3((int)(ncol / 256)), dim3(256), 0, stream>>>(
        pm, ps, pa, diag, out);
}